// Round 1
// baseline (194.862 us; speedup 1.0000x reference)
//
#include <hip/hip_runtime.h>

#define BB   128
#define JJ   17
#define YY   96
#define XX   72
#define YX   (YY * XX)        // 6912
#define NQ   (BB * JJ)        // 2176
#define NTOT (NQ * YX)        // 15040512 elements per channel

__global__ void zero_out_kernel(float* out) {
    out[0] = 0.0f;
}

__global__ __launch_bounds__(256) void regloss_kernel(
    const float* __restrict__ loc,    // (2, B, J, Y, X)
    const float* __restrict__ cord,   // (2, J, B)
    const float* __restrict__ tw,     // (B, J, 1)
    float* __restrict__ out)
{
    const int q  = blockIdx.x;        // q = b*J + j, 0..NQ-1
    const int jj = q >> 7;            // q / 128  (index into cord's J dim)
    const int bb = q & 127;           // q % 128  (index into cord's B dim)

    const float cx = cord[jj * BB + bb];
    const float cy = cord[JJ * BB + jj * BB + bb];
    const float w  = tw[q];

    const float4* loc0 = (const float4*)(loc + (size_t)q * YX);
    const float4* loc1 = (const float4*)(loc + (size_t)NTOT + (size_t)q * YX);

    float acc = 0.0f;
    // YX/4 = 1728 float4s per block, 256 threads -> 6-7 iters/thread
    for (int i = threadIdx.x; i < YX / 4; i += 256) {
        const int p  = i * 4;
        const int yy = p / XX;            // constant-divide -> magic mul
        const int xx = p - yy * XX;       // 4-aligned, never crosses a row (72 % 4 == 0)

        float4 lx = loc0[i];
        float4 ly = loc1[i];

        const float gy = (float)(int)((float)yy - cy);   // trunc toward zero, as np int32 cast
        const float gyw = gy * w;

        #pragma unroll
        for (int k = 0; k < 4; ++k) {
            const float gx = (float)(int)((float)(xx + k) - cx);
            const float dx = (&lx.x)[k] * w - gx * w;
            acc += dx * dx;
            const float dy = (&ly.x)[k] * w - gyw;
            acc += dy * dy;
        }
    }

    // wave64 shuffle reduction
    #pragma unroll
    for (int off = 32; off > 0; off >>= 1)
        acc += __shfl_down(acc, off, 64);

    __shared__ float wsum[4];
    const int lane = threadIdx.x & 63;
    const int wave = threadIdx.x >> 6;
    if (lane == 0) wsum[wave] = acc;
    __syncthreads();

    if (threadIdx.x == 0) {
        const float s = wsum[0] + wsum[1] + wsum[2] + wsum[3];
        const float scale = 0.5f / (float)NTOT;   // 0.5 / (J * B * YX)
        atomicAdd(out, s * scale);
    }
}

extern "C" void kernel_launch(void* const* d_in, const int* in_sizes, int n_in,
                              void* d_out, int out_size, void* d_ws, size_t ws_size,
                              hipStream_t stream) {
    const float* loc  = (const float*)d_in[0];   // (2,128,17,96,72) fp32
    const float* cord = (const float*)d_in[1];   // (2,17,128) fp32
    const float* tw   = (const float*)d_in[2];   // (128,17,1) fp32
    float* out = (float*)d_out;

    zero_out_kernel<<<1, 1, 0, stream>>>(out);
    regloss_kernel<<<NQ, 256, 0, stream>>>(loc, cord, tw, out);
}

// Round 2
// 178.666 us; speedup vs baseline: 1.0906x; 1.0906x over previous
//
#include <hip/hip_runtime.h>

#define BB   128
#define JJ   17
#define YY   96
#define XX   72
#define YX   (YY * XX)        // 6912
#define NQ   (BB * JJ)        // 2176 blocks / partials
#define NTOT (NQ * YX)        // 15040512 elements per channel

// Stage 1: one block per q = b*J + j. Writes one fp32 partial per block to ws.
__global__ __launch_bounds__(256) void regloss_partial_kernel(
    const float* __restrict__ loc,    // (2, B, J, Y, X)
    const float* __restrict__ cord,   // (2, J, B)
    const float* __restrict__ tw,     // (B, J, 1)
    float* __restrict__ partial)      // (NQ,) in d_ws
{
    const int q  = blockIdx.x;
    const int jj = q >> 7;            // q / 128
    const int bb = q & 127;           // q % 128

    const float cx = cord[jj * BB + bb];
    const float cy = cord[JJ * BB + jj * BB + bb];
    const float w  = tw[q];

    const float4* loc0 = (const float4*)(loc + (size_t)q * YX);
    const float4* loc1 = (const float4*)(loc + (size_t)NTOT + (size_t)q * YX);

    float acc = 0.0f;
    // YX/4 = 1728 float4s per channel per block; 256 threads -> 6-7 iters
    for (int i = threadIdx.x; i < YX / 4; i += 256) {
        const int p  = i * 4;
        const int yy = p / XX;            // magic-mul constant divide
        const int xx = p - yy * XX;       // 72 % 4 == 0: float4 never crosses a row

        float4 lx = loc0[i];
        float4 ly = loc1[i];

        const float gy  = (float)(int)((float)yy - cy);   // trunc like np int32 cast
        const float gyw = gy * w;

        #pragma unroll
        for (int k = 0; k < 4; ++k) {
            const float gx = (float)(int)((float)(xx + k) - cx);
            const float dx = fmaf((&lx.x)[k], w, -gx * w);
            acc = fmaf(dx, dx, acc);
            const float dy = fmaf((&ly.x)[k], w, -gyw);
            acc = fmaf(dy, dy, acc);
        }
    }

    // wave64 shuffle reduction
    #pragma unroll
    for (int off = 32; off > 0; off >>= 1)
        acc += __shfl_down(acc, off, 64);

    __shared__ float wsum[4];
    const int lane = threadIdx.x & 63;
    const int wave = threadIdx.x >> 6;
    if (lane == 0) wsum[wave] = acc;
    __syncthreads();

    if (threadIdx.x == 0)
        partial[blockIdx.x] = wsum[0] + wsum[1] + wsum[2] + wsum[3];
}

// Stage 2: single block folds the 2176 partials, scales, stores the scalar.
__global__ __launch_bounds__(256) void regloss_final_kernel(
    const float* __restrict__ partial, float* __restrict__ out)
{
    float acc = 0.0f;
    for (int i = threadIdx.x; i < NQ; i += 256)
        acc += partial[i];

    #pragma unroll
    for (int off = 32; off > 0; off >>= 1)
        acc += __shfl_down(acc, off, 64);

    __shared__ float wsum[4];
    const int lane = threadIdx.x & 63;
    const int wave = threadIdx.x >> 6;
    if (lane == 0) wsum[wave] = acc;
    __syncthreads();

    if (threadIdx.x == 0) {
        const float s = wsum[0] + wsum[1] + wsum[2] + wsum[3];
        out[0] = s * (0.5f / (float)NTOT);   // 0.5 / (J * B * YX)
    }
}

extern "C" void kernel_launch(void* const* d_in, const int* in_sizes, int n_in,
                              void* d_out, int out_size, void* d_ws, size_t ws_size,
                              hipStream_t stream) {
    const float* loc  = (const float*)d_in[0];   // (2,128,17,96,72) fp32
    const float* cord = (const float*)d_in[1];   // (2,17,128) fp32
    const float* tw   = (const float*)d_in[2];   // (128,17,1) fp32
    float* partial = (float*)d_ws;               // NQ floats, overwritten each call
    float* out = (float*)d_out;

    regloss_partial_kernel<<<NQ, 256, 0, stream>>>(loc, cord, tw, partial);
    regloss_final_kernel<<<1, 256, 0, stream>>>(partial, out);
}

// Round 3
// 174.301 us; speedup vs baseline: 1.1180x; 1.0250x over previous
//
#include <hip/hip_runtime.h>

#define BB   128
#define JJ   17
#define YY   96
#define XX   72
#define YX   (YY * XX)        // 6912 floats per (b,j) per channel
#define N4   (YX / 4)         // 1728 float4s
#define NQ   (BB * JJ)        // 2176 blocks / partials
#define NTOT (NQ * YX)        // 15040512 elements per channel
#define UNI  6                // uniform float4 iters/thread (6*256 = 1536)
#define TAIL (N4 - UNI * 256) // 192 remaining float4s (threads 0..191)

// Sum of squared diffs for one float4 pair at float4-index i within a q-tile.
// yy = (4i)/72 = i/18 ; xx = (i%18)*4. gt uses trunc-toward-zero (np int32 cast).
__device__ __forceinline__ float tile_term(float4 lx, float4 ly, int i,
                                           float cx, float cy) {
    const int yy = i / 18;                // magic-mul constant divide
    const int xx = (i - yy * 18) * 4;
    const float gy = (float)(int)((float)yy - cy);
    float s = 0.0f;
    #pragma unroll
    for (int k = 0; k < 4; ++k) {
        const float gx = (float)(int)((float)(xx + k) - cx);
        const float dx = (&lx.x)[k] - gx;
        s = fmaf(dx, dx, s);
        const float dy = (&ly.x)[k] - gy;
        s = fmaf(dy, dy, s);
    }
    return s;
}

// Stage 1: one block per q = b*J + j. All global loads issued up-front
// (12 uniform float4s + tail pair) so each wave has ~200 B/lane in flight.
__global__ __launch_bounds__(256) void regloss_partial_kernel(
    const float* __restrict__ loc,    // (2, B, J, Y, X)
    const float* __restrict__ cord,   // (2, J, B)
    const float* __restrict__ tw,     // (B, J, 1)
    float* __restrict__ partial)      // (NQ,) in d_ws
{
    const int tid = threadIdx.x;
    const int q  = blockIdx.x;
    const int jj = q >> 7;            // q / 128
    const int bb = q & 127;           // q % 128

    const float cx = cord[jj * BB + bb];
    const float cy = cord[JJ * BB + jj * BB + bb];
    const float w  = tw[q];

    const float4* loc0 = (const float4*)(loc + (size_t)q * YX);
    const float4* loc1 = (const float4*)(loc + (size_t)NTOT + (size_t)q * YX);

    float4 lx[UNI + 1], ly[UNI + 1];
    #pragma unroll
    for (int k = 0; k < UNI; ++k) lx[k] = loc0[tid + 256 * k];
    #pragma unroll
    for (int k = 0; k < UNI; ++k) ly[k] = loc1[tid + 256 * k];
    const bool has_tail = tid < TAIL;
    if (has_tail) {
        lx[UNI] = loc0[UNI * 256 + tid];
        ly[UNI] = loc1[UNI * 256 + tid];
    }

    float acc = 0.0f;
    #pragma unroll
    for (int k = 0; k < UNI; ++k)
        acc += tile_term(lx[k], ly[k], tid + 256 * k, cx, cy);
    if (has_tail)
        acc += tile_term(lx[UNI], ly[UNI], UNI * 256 + tid, cx, cy);

    // wave64 shuffle reduction
    #pragma unroll
    for (int off = 32; off > 0; off >>= 1)
        acc += __shfl_down(acc, off, 64);

    __shared__ float wsum[4];
    const int lane = tid & 63;
    const int wave = tid >> 6;
    if (lane == 0) wsum[wave] = acc;
    __syncthreads();

    if (tid == 0)   // w is uniform per block: apply w^2 once here
        partial[q] = (w * w) * (wsum[0] + wsum[1] + wsum[2] + wsum[3]);
}

// Stage 2: single block folds the 2176 partials, scales, stores the scalar.
__global__ __launch_bounds__(256) void regloss_final_kernel(
    const float* __restrict__ partial, float* __restrict__ out)
{
    float acc = 0.0f;
    for (int i = threadIdx.x; i < NQ; i += 256)
        acc += partial[i];

    #pragma unroll
    for (int off = 32; off > 0; off >>= 1)
        acc += __shfl_down(acc, off, 64);

    __shared__ float wsum[4];
    const int lane = threadIdx.x & 63;
    const int wave = threadIdx.x >> 6;
    if (lane == 0) wsum[wave] = acc;
    __syncthreads();

    if (threadIdx.x == 0) {
        const float s = wsum[0] + wsum[1] + wsum[2] + wsum[3];
        out[0] = s * (0.5f / (float)NTOT);   // 0.5 / (J * B * YX)
    }
}

extern "C" void kernel_launch(void* const* d_in, const int* in_sizes, int n_in,
                              void* d_out, int out_size, void* d_ws, size_t ws_size,
                              hipStream_t stream) {
    const float* loc  = (const float*)d_in[0];   // (2,128,17,96,72) fp32
    const float* cord = (const float*)d_in[1];   // (2,17,128) fp32
    const float* tw   = (const float*)d_in[2];   // (128,17,1) fp32
    float* partial = (float*)d_ws;               // NQ floats, overwritten each call
    float* out = (float*)d_out;

    regloss_partial_kernel<<<NQ, 256, 0, stream>>>(loc, cord, tw, partial);
    regloss_final_kernel<<<1, 256, 0, stream>>>(partial, out);
}